// Round 3
// baseline (2158.414 us; speedup 1.0000x reference)
//
#include <hip/hip_runtime.h>
#include <cstdint>

#define N_NODES 8192
#define D_OSC   64
#define E_EDGE  1048576   // both E_K and E_HK
#define NBUCKET 512       // node buckets (16 nodes each)
#define NPB     16        // nodes per bucket
#define BCAP    12288     // record capacity per bucket (mean 8192, +45 sigma)
#define CHUNK   2048      // edges per coeff block

__device__ __forceinline__ float waveReduceSum(float v) {
#pragma unroll
  for (int off = 32; off > 0; off >>= 1)
    v += __shfl_xor(v, off, 64);
  return v;
}

// g = tanh(state_H); zero accumulators + bucket cursors (ws poisoned 0xAA)
__global__ void k_prep(const float* __restrict__ sH, float* g, float* y1, float* y2,
                       float* fH, int* cursor) {
  int i = blockIdx.x * blockDim.x + threadIdx.x;
  if (i < N_NODES) {
    g[i] = tanhf(sH[i]);
    y1[i] = 0.f;
    y2[i] = 0.f;
    fH[i] = 0.f;
  }
  if (i < NBUCKET) cursor[i] = 0;
}

// row-normalize state_K -> sK ; one wave per node, lane = dim
__global__ void k_normalize(const float* __restrict__ stateK, float* __restrict__ sK) {
  int node = blockIdx.x * (blockDim.x >> 6) + (threadIdx.x >> 6);
  int lane = threadIdx.x & 63;
  float v = stateK[node * D_OSC + lane];
  float ss = waveReduceSum(v * v);
  sK[node * D_OSC + lane] = v / sqrtf(ss);
}

// Fused coeff + bucket-binned scatter.
// 16-lane group per edge (4 edges/wave), float4 row loads for the 64-dim dot.
// Per edge -> two 8B records {other | node_local<<16, cf} staged in LDS, then
// written destination-grouped (full-line writes). f_H edge terms go straight
// to fH via HW fp32 atomics.
__global__ __launch_bounds__(256) void k_coeff_scatter(
    const float* __restrict__ sK, const int2* __restrict__ indK,
    const int2* __restrict__ indHK, const float* __restrict__ wK,
    const float* __restrict__ wHK, const float* __restrict__ g,
    const float* __restrict__ kH, const float* __restrict__ kK,
    int* cursor, float* fH, int2* __restrict__ recs) {
  __shared__ int2     recS[2 * CHUNK];   // 32 KB
  __shared__ unsigned keyS[2 * CHUNK];   // 16 KB
  __shared__ int      histS[NBUCKET];    // 2 KB
  __shared__ int      baseS[NBUCKET];    // 2 KB
  int t = threadIdx.x;
  for (int s = t; s < NBUCKET; s += 256) histS[s] = 0;
  __syncthreads();

  int l16 = t & 15;
  int grp = t >> 4;  // 0..15 groups per block
  int set = (int)(blockIdx.x >= (E_EDGE / CHUNK));
  const int2* ind = set ? indHK : indK;
  int e0 = blockIdx.x * CHUNK - set * E_EDGE;
  float rKH = 1.f / kH[0];
  float rKK = 1.f / kK[0];
  const float4* sK4 = (const float4*)sK;

  for (int i = 0; i < CHUNK / 16; ++i) {
    int el = i * 16 + grp;          // edge slot within block
    int e = e0 + el;
    int2 pr = ind[e];
    float4 a = sK4[pr.x * 16 + l16];
    float4 b = sK4[pr.y * 16 + l16];
    float d = a.x * b.x + a.y * b.y + a.z * b.z + a.w * b.w;
#pragma unroll
    for (int off = 8; off > 0; off >>= 1) d += __shfl_xor(d, off, 64);
    if (l16 == 0) {
      float cf;
      if (set) {
        float ww = wHK[e];
        float ch = d * ww * rKH;
        float gx = g[pr.x], gy = g[pr.y];
        cf = -gx * gy * ww * rKK;
        unsafeAtomicAdd(&fH[pr.x], ch * gy);
        unsafeAtomicAdd(&fH[pr.y], ch * gx);
      } else {
        cf = wK[e] * d;
      }
      int bx = pr.x >> 4, by = pr.y >> 4;
      int rx = atomicAdd(&histS[bx], 1);
      int ry = atomicAdd(&histS[by], 1);
      recS[2 * el]     = make_int2(pr.y | ((pr.x & (NPB - 1)) << 16), __float_as_int(cf));
      keyS[2 * el]     = ((unsigned)bx << 16) | (unsigned)rx;
      recS[2 * el + 1] = make_int2(pr.x | ((pr.y & (NPB - 1)) << 16), __float_as_int(cf));
      keyS[2 * el + 1] = ((unsigned)by << 16) | (unsigned)ry;
    }
  }
  __syncthreads();
  for (int s = t; s < NBUCKET; s += 256)
    baseS[s] = atomicAdd(&cursor[s], histS[s]);
  __syncthreads();
  for (int s = t; s < 2 * CHUNK; s += 256) {
    unsigned k = keyS[s];
    int bkt = k >> 16;
    recs[(size_t)bkt * BCAP + baseS[bkt] + (k & 0xFFFFu)] = recS[s];
  }
}

// one streaming pass over W: y1 = W@g, y2 = W^T@g
#define MV_ROWS 32
#define MV_CB   2048
__global__ __launch_bounds__(256) void k_matvec(const float* __restrict__ W,
                                                const float* __restrict__ g,
                                                float* y1, float* y2) {
  int t = threadIdx.x;
  int r0 = blockIdx.x * MV_ROWS;
  int c0 = blockIdx.y * MV_CB;
  int wid = t >> 6, lane = t & 63;
  float gcol[8], y2p[8];
#pragma unroll
  for (int k = 0; k < 8; ++k) { gcol[k] = g[c0 + t + 256 * k]; y2p[k] = 0.f; }
  __shared__ float red[MV_ROWS][4];
  for (int r = 0; r < MV_ROWS; ++r) {
    int i = r0 + r;
    float gi = g[i];
    const float* row = W + (size_t)i * N_NODES + c0 + t;
    float acc = 0.f;
#pragma unroll
    for (int k = 0; k < 8; ++k) {
      float w = row[256 * k];
      acc = fmaf(w, gcol[k], acc);
      y2p[k] = fmaf(w, gi, y2p[k]);
    }
    acc = waveReduceSum(acc);
    if (lane == 0) red[r][wid] = acc;
  }
  __syncthreads();
  if (t < MV_ROWS)
    atomicAdd(&y1[r0 + t], red[t][0] + red[t][1] + red[t][2] + red[t][3]);
#pragma unroll
  for (int k = 0; k < 8; ++k) atomicAdd(&y2[c0 + t + 256 * k], y2p[k]);
}

// one block per bucket: LDS f[16][64] accumulator, stream records, ds_add_f32,
// then projection + f_H epilogue.
__global__ __launch_bounds__(512) void k_gather(
    const float* __restrict__ sK, const int* __restrict__ cursor,
    const int2* __restrict__ recs, const float* __restrict__ fH,
    const float* __restrict__ y1, const float* __restrict__ y2,
    const float* __restrict__ sH, const float* __restrict__ bias,
    float* __restrict__ out) {
  __shared__ float fld[NPB * D_OSC];  // 4 KB
  int b = blockIdx.x;
  int t = threadIdx.x;
  for (int s = t; s < NPB * D_OSC; s += 512) fld[s] = 0.f;
  __syncthreads();
  int cnt = cursor[b];
  const int2* rb = recs + (size_t)b * BCAP;
  int wave = t >> 6, lane = t & 63;

  int ntile = cnt >> 4;  // full 16-record tiles
  for (int i = wave; i < ntile; i += 8) {
    int p0 = i << 4;
    int2 r = rb[p0 + (lane & 15)];
#pragma unroll
    for (int j = 0; j < 16; ++j) {
      int w0 = __shfl(r.x, j, 64);
      float cf = __int_as_float(__shfl(r.y, j, 64));
      float v = sK[(w0 & 0xFFFF) * D_OSC + lane];
      atomicAdd(&fld[(w0 >> 16) * D_OSC + lane], cf * v);
    }
  }
  if (wave == 0) {
    int p0 = ntile << 4;
    int tail = cnt - p0;
    if (tail > 0) {
      int2 r = rb[p0 + (lane & 15)];
      for (int j = 0; j < tail; ++j) {
        int w0 = __shfl(r.x, j, 64);
        float cf = __int_as_float(__shfl(r.y, j, 64));
        float v = sK[(w0 & 0xFFFF) * D_OSC + lane];
        atomicAdd(&fld[(w0 >> 16) * D_OSC + lane], cf * v);
      }
    }
  }
  __syncthreads();
  // f_K = -f + sK * (sK . f)
  for (int n = wave; n < NPB; n += 8) {
    int node = b * NPB + n;
    float fv = fld[n * D_OSC + lane];
    float skl = sK[node * D_OSC + lane];
    float dot = waveReduceSum(skl * fv);
    out[N_NODES + node * D_OSC + lane] = fmaf(skl, dot, -fv);
  }
  if (t < NPB) {
    int node = b * NPB + t;
    out[node] = fH[node] + 0.5f * (y1[node] + y2[node]) - sH[node] + bias[node];
  }
}

extern "C" void kernel_launch(void* const* d_in, const int* in_sizes, int n_in,
                              void* d_out, int out_size, void* d_ws, size_t ws_size,
                              hipStream_t stream) {
  const float* state_H    = (const float*)d_in[0];
  const float* state_K    = (const float*)d_in[1];
  const int2*  ind_K      = (const int2*)d_in[2];
  const int2*  ind_HK     = (const int2*)d_in[3];
  const float* kappa_K    = (const float*)d_in[4];
  const float* kappa_H    = (const float*)d_in[5];
  const float* weights_H  = (const float*)d_in[6];
  const float* bias_H     = (const float*)d_in[7];
  const float* weights_HK = (const float*)d_in[8];
  const float* w_K        = (const float*)d_in[9];
  float* out = (float*)d_out;

  char* w = (char*)d_ws;
  float* sK   = (float*)w; w += (size_t)N_NODES * D_OSC * 4;  // 2 MB
  float* g    = (float*)w; w += (size_t)N_NODES * 4;
  float* y1   = (float*)w; w += (size_t)N_NODES * 4;
  float* y2   = (float*)w; w += (size_t)N_NODES * 4;
  float* fH   = (float*)w; w += (size_t)N_NODES * 4;
  int*   curs = (int*)w;   w += (size_t)NBUCKET * 4;
  w = (char*)(((uintptr_t)w + 255) & ~(uintptr_t)255);
  int2*  recs = (int2*)w;  // 512 * 12288 * 8B = 50.3 MB

  k_prep<<<N_NODES / 256, 256, 0, stream>>>(state_H, g, y1, y2, fH, curs);
  k_normalize<<<N_NODES / 4, 256, 0, stream>>>(state_K, sK);
  k_coeff_scatter<<<2 * E_EDGE / CHUNK, 256, 0, stream>>>(
      sK, ind_K, ind_HK, w_K, weights_HK, g, kappa_H, kappa_K, curs, fH, recs);
  k_matvec<<<dim3(N_NODES / MV_ROWS, N_NODES / MV_CB), 256, 0, stream>>>(weights_H, g,
                                                                         y1, y2);
  k_gather<<<NBUCKET, 512, 0, stream>>>(sK, curs, recs, fH, y1, y2, state_H, bias_H,
                                        out);
}